// Round 3
// baseline (2343.489 us; speedup 1.0000x reference)
//
#include <hip/hip_runtime.h>

// ---------------------------------------------------------------------------
// Graph-conv LSTM encoder, B=4 T=12 N=4096 F=32, NG=14 gates.
// R3: barrier-free, atomic-free adj GEMM. Per step:
//   gemm1 = adj@[h | x_t] (64 cols), gemm2 = adj@[h_mid | m] (64 cols).
// Each gemm: grid (64 row-tiles, 4 K-slices, B), 4 waves/block, each wave
// computes 16 rows x 64 cols over its 1024-wide K slice with A and B read
// DIRECTLY from global (no LDS, no __syncthreads) -> compiler vmcnt pipeline
// + 16 waves/CU TLP. Split-K partials stored per-slice (fp32, 16 MB); gates
// kernels sum the 4 partials on read. adj converted to bf16 once (134 MB).
// ---------------------------------------------------------------------------

typedef __bf16 bf16_t;
typedef __bf16 bf16x8 __attribute__((ext_vector_type(8)));
typedef float  f32x4  __attribute__((ext_vector_type(4)));

#define DI __device__ __forceinline__

#define BB 4
#define TT 12
#define NN 4096
#define FF 32

DI float sigm(float x)  { return __builtin_amdgcn_rcpf(1.f + __expf(-x)); }
DI float tanh_f(float x){ float e = __expf(2.f * x); return 1.f - 2.f * __builtin_amdgcn_rcpf(e + 1.f); }

// ---------------- adj fp32 -> bf16 (8 elements / thread) --------------------
// NT loads: don't let the 268 MB fp32 stream evict adj_bf from L3.
__global__ __launch_bounds__(256) void conv_adj_k(const float* __restrict__ a,
                                                  bf16_t* __restrict__ o) {
    size_t i = ((size_t)blockIdx.x * 256 + threadIdx.x) * 8;
    f32x4 v0 = __builtin_nontemporal_load((const f32x4*)(a + i));
    f32x4 v1 = __builtin_nontemporal_load((const f32x4*)(a + i + 4));
    union { uint4 u; bf16_t h[8]; } t;
#pragma unroll
    for (int j = 0; j < 4; ++j) { t.h[j] = (bf16_t)v0[j]; t.h[4 + j] = (bf16_t)v1[j]; }
    *(uint4*)(o + i) = t.u;
}

// ---------------- x [B,T,N,F] fp32 -> xT [B, T*F, N] bf16 -------------------
__global__ __launch_bounds__(256) void xpose_k(const float* __restrict__ x,
                                               bf16_t* __restrict__ xT) {
    const int b = blockIdx.z, t = blockIdx.y, n0 = blockIdx.x * 64;
    const int tid = threadIdx.x;
    __shared__ float tile[64][33];
    const float* src = x + (((size_t)(b * TT + t)) * NN + n0) * FF;
#pragma unroll
    for (int rr = 0; rr < 2; ++rr) {
        int idx = rr * 256 + tid;
        int row = idx >> 3, seg = idx & 7;
        float4 v = *(const float4*)(src + row * FF + seg * 4);
        tile[row][seg * 4 + 0] = v.x; tile[row][seg * 4 + 1] = v.y;
        tile[row][seg * 4 + 2] = v.z; tile[row][seg * 4 + 3] = v.w;
    }
    __syncthreads();
    const int f = tid >> 3, seg = tid & 7;
    union { uint4 u; bf16_t h[8]; } o;
#pragma unroll
    for (int j = 0; j < 8; ++j) o.h[j] = (bf16_t)tile[seg * 8 + j][f];
    *(uint4*)&xT[((size_t)(b * 384 + t * FF + f)) * NN + n0 + seg * 8] = o.u;
}

// ---------------- W [14,32,64] fp32 -> MFMA B-fragments bf16 ----------------
__global__ __launch_bounds__(256) void make_wfrag_k(const float* __restrict__ W,
                                                    bf16_t* __restrict__ Wf) {
    const int g = blockIdx.x, tid = threadIdx.x;
    const int ct = tid >> 6, lane = tid & 63;
    const int k0 = (lane >> 4) * 8, col = ct * 16 + (lane & 15);
    union { uint4 u; bf16_t h[8]; } t;
#pragma unroll
    for (int j = 0; j < 8; ++j) t.h[j] = (bf16_t)W[(g * 32 + k0 + j) * 64 + col];
    *(uint4*)&Wf[((g * 4 + ct) * 64 + lane) * 8] = t.u;
}

// ---------------- init: h=c=m=1 ---------------------------------------------
__global__ __launch_bounds__(256) void init_k(bf16_t* h_bf, bf16_t* hm_bf,
                                              float* c, float* m) {
    const int idx = blockIdx.x * 256 + threadIdx.x;   // 524288 = B*N*32
    const int b = idx >> 17, r = idx & 131071;
    h_bf[idx] = (bf16_t)1.f;
    hm_bf[(size_t)b * 262144 + 131072 + r] = (bf16_t)1.f;   // m half of [h_mid|m]
    c[idx] = 1.f;
    m[idx] = 1.f;
}

// ---------------- direct GEMM: Yp[b][slice] = adjslice @ [p0|p1]^T ----------
// Grid (64, 4, B), 256 thr = 4 waves. Wave w: rows row0+w*16..+15, all 64
// cols, K in [slice*1024, +1024). A row stream + B panel (L2-hot) read direct
// from global as bf16x8; no LDS, no barriers. Partials: Yp[((b*4+slice)*N)+row][col].
template <bool ABF, int S, int BS0, int BS1>
__global__ __launch_bounds__(256, 4) void gemm_direct(const void* __restrict__ Ap,
                                                      const bf16_t* __restrict__ p0,
                                                      const bf16_t* __restrict__ p1,
                                                      float* __restrict__ Yp) {
    const int b = blockIdx.z, slice = blockIdx.y;
    const int row0 = blockIdx.x * 64;
    const int tid = threadIdx.x, wave = tid >> 6, lane = tid & 63;
    const int mrow = lane & 15, quad = lane >> 4;
    const int row = row0 + wave * 16 + mrow;
    const int k0 = slice * 1024 + quad * 8;
    const bf16_t* bp[4];
#pragma unroll
    for (int ct = 0; ct < 4; ++ct) {
        const int col = ct * 16 + mrow;
        bp[ct] = (ct * 16 < S ? p0 + ((size_t)b * BS0 + col) * NN
                              : p1 + ((size_t)b * BS1 + (col - S)) * NN) + k0;
    }
    const f32x4 zero = {0.f, 0.f, 0.f, 0.f};
    f32x4 acc[4] = {zero, zero, zero, zero};
    if constexpr (ABF) {
        const bf16_t* ap = (const bf16_t*)Ap + ((size_t)b << 24) + (size_t)row * NN + k0;
#pragma unroll 4
        for (int kk = 0; kk < 32; ++kk) {
            bf16x8 af = *(const bf16x8*)(ap + kk * 32);
#pragma unroll
            for (int ct = 0; ct < 4; ++ct) {
                bf16x8 bfr = *(const bf16x8*)(bp[ct] + kk * 32);
                acc[ct] = __builtin_amdgcn_mfma_f32_16x16x32_bf16(af, bfr, acc[ct], 0, 0, 0);
            }
        }
    } else {
        const float* ap = (const float*)Ap + ((size_t)b << 24) + (size_t)row * NN + k0;
#pragma unroll 4
        for (int kk = 0; kk < 32; ++kk) {
            f32x4 v0 = *(const f32x4*)(ap + kk * 32);
            f32x4 v1 = *(const f32x4*)(ap + kk * 32 + 4);
            bf16x8 af;
#pragma unroll
            for (int j = 0; j < 4; ++j) { af[j] = (bf16_t)v0[j]; af[4 + j] = (bf16_t)v1[j]; }
#pragma unroll
            for (int ct = 0; ct < 4; ++ct) {
                bf16x8 bfr = *(const bf16x8*)(bp[ct] + kk * 32);
                acc[ct] = __builtin_amdgcn_mfma_f32_16x16x32_bf16(af, bfr, acc[ct], 0, 0, 0);
            }
        }
    }
    float* yb = Yp + (((size_t)b * 4 + slice) * NN + row0 + wave * 16 + quad * 4) * 64 + mrow;
#pragma unroll
    for (int ct = 0; ct < 4; ++ct)
#pragma unroll
        for (int r = 0; r < 4; ++r)
            yb[(size_t)r * 64 + ct * 16] = acc[ct][r];
}

// ---------------- gate kernel 1: gates 0..7 -> c_new, h_mid -----------------
// Y1 partials: [b][slice][N][64]; cols 0..31 = adj@h, 32..63 = adj@x_t.
__global__ __launch_bounds__(256) void gates1_k(const float* __restrict__ Y1,
                                                const bf16_t* __restrict__ Wf,
                                                const float* __restrict__ bias,
                                                float* __restrict__ c,
                                                bf16_t* __restrict__ hm_bf) {
    const int b = blockIdx.y, n0 = blockIdx.x * 64;
    const int tid = threadIdx.x, wave = tid >> 6, lane = tid & 63;
    const int mrow = lane & 15, quad = lane >> 4;
    const int nw = n0 + wave * 16;
    const f32x4 zero = {0.f, 0.f, 0.f, 0.f};
    const float* yr = Y1 + (((size_t)b * 4) * NN + nw + mrow) * 64 + quad * 8;
    f32x4 h0 = zero, h1 = zero, x0 = zero, x1 = zero;
#pragma unroll
    for (int s = 0; s < 4; ++s) {
        const float* p = yr + (size_t)s * NN * 64;
        h0 += *(const f32x4*)(p);
        h1 += *(const f32x4*)(p + 4);
        x0 += *(const f32x4*)(p + 32);
        x1 += *(const f32x4*)(p + 36);
    }
    bf16x8 ah, ax;
#pragma unroll
    for (int j = 0; j < 4; ++j) {
        ah[j] = (bf16_t)h0[j]; ah[4 + j] = (bf16_t)h1[j];
        ax[j] = (bf16_t)x0[j]; ax[4 + j] = (bf16_t)x1[j];
    }
    float gate[4][2][4];   // f, i, cg(tanh), o
#pragma unroll
    for (int gi = 0; gi < 4; ++gi) {
        const int ge = 2 * gi, go = ge + 1;
        f32x4 ze[4], zo[4];
#pragma unroll
        for (int ct = 0; ct < 4; ++ct) {
            bf16x8 we = *(const bf16x8*)&Wf[((ge * 4 + ct) * 64 + lane) * 8];
            bf16x8 wo = *(const bf16x8*)&Wf[((go * 4 + ct) * 64 + lane) * 8];
            ze[ct] = __builtin_amdgcn_mfma_f32_16x16x32_bf16(ax, we, zero, 0, 0, 0);
            zo[ct] = __builtin_amdgcn_mfma_f32_16x16x32_bf16(ah, wo, zero, 0, 0, 0);
            const float be = bias[ge * 64 + ct * 16 + mrow];
            const float bo = bias[go * 64 + ct * 16 + mrow];
#pragma unroll
            for (int r = 0; r < 4; ++r) { ze[ct][r] += be; zo[ct][r] += bo; }
        }
#pragma unroll
        for (int p = 0; p < 2; ++p)
#pragma unroll
            for (int r = 0; r < 4; ++r) {
                float s = ze[p][r] * sigm(ze[p + 2][r]) + zo[p][r] * sigm(zo[p + 2][r]);
                gate[gi][p][r] = (gi == 2) ? tanh_f(s) : sigm(s);
            }
    }
    __shared__ bf16_t hmT[32][64];
#pragma unroll
    for (int p = 0; p < 2; ++p)
#pragma unroll
        for (int r = 0; r < 4; ++r) {
            const int row = nw + quad * 4 + r, col = p * 16 + mrow;
            const size_t ci = ((size_t)b * NN + row) * FF + col;
            float cn = gate[0][p][r] * c[ci] + gate[1][p][r] * gate[2][p][r];
            c[ci] = cn;
            hmT[col][wave * 16 + quad * 4 + r] = (bf16_t)(gate[3][p][r] * tanh_f(cn));
        }
    __syncthreads();
    {   // transposed coalesced write: hm_bf[b][col][n]
        const int col = tid >> 3, seg = tid & 7;
        union { uint4 u; bf16_t h[8]; } o;
#pragma unroll
        for (int j = 0; j < 8; ++j) o.h[j] = hmT[col][seg * 8 + j];
        *(uint4*)&hm_bf[((size_t)b * 64 + col) * NN + n0 + seg * 8] = o.u;
    }
}

// ---------------- gate kernel 2: gates 8..13 -> m_new, h_new ----------------
// Y2 partials: [b][slice][N][64]; cols 0..31 = adj@h_mid, 32..63 = adj@m.
__global__ __launch_bounds__(256) void gates2_k(const float* __restrict__ Y2,
                                                const bf16_t* __restrict__ Wf,
                                                const float* __restrict__ bias,
                                                float* __restrict__ m,
                                                bf16_t* __restrict__ hm_bf,
                                                bf16_t* __restrict__ h_bf,
                                                float* __restrict__ hs, int t) {
    const int b = blockIdx.y, n0 = blockIdx.x * 64;
    const int tid = threadIdx.x, wave = tid >> 6, lane = tid & 63;
    const int mrow = lane & 15, quad = lane >> 4;
    const int nw = n0 + wave * 16;
    const f32x4 zero = {0.f, 0.f, 0.f, 0.f};
    const float* yr = Y2 + (((size_t)b * 4) * NN + nw + mrow) * 64 + quad * 8;
    f32x4 h0 = zero, h1 = zero, m0 = zero, m1 = zero;
#pragma unroll
    for (int s = 0; s < 4; ++s) {
        const float* p = yr + (size_t)s * NN * 64;
        h0 += *(const f32x4*)(p);
        h1 += *(const f32x4*)(p + 4);
        m0 += *(const f32x4*)(p + 32);
        m1 += *(const f32x4*)(p + 36);
    }
    bf16x8 axh, axm;
#pragma unroll
    for (int j = 0; j < 4; ++j) {
        axh[j] = (bf16_t)h0[j]; axh[4 + j] = (bf16_t)h1[j];
        axm[j] = (bf16_t)m0[j]; axm[4 + j] = (bf16_t)m1[j];
    }
    float gate[3][2][4];   // i2, gg, o2
#pragma unroll
    for (int gi = 0; gi < 3; ++gi) {
        const int ge = 8 + 2 * gi, go = ge + 1;
        f32x4 ze[4], zo[4];
#pragma unroll
        for (int ct = 0; ct < 4; ++ct) {
            bf16x8 we = *(const bf16x8*)&Wf[((ge * 4 + ct) * 64 + lane) * 8];
            bf16x8 wo = *(const bf16x8*)&Wf[((go * 4 + ct) * 64 + lane) * 8];
            ze[ct] = __builtin_amdgcn_mfma_f32_16x16x32_bf16(axh, we, zero, 0, 0, 0);
            zo[ct] = __builtin_amdgcn_mfma_f32_16x16x32_bf16(axm, wo, zero, 0, 0, 0);
            const float be = bias[ge * 64 + ct * 16 + mrow];
            const float bo = bias[go * 64 + ct * 16 + mrow];
#pragma unroll
            for (int r = 0; r < 4; ++r) { ze[ct][r] += be; zo[ct][r] += bo; }
        }
#pragma unroll
        for (int p = 0; p < 2; ++p)
#pragma unroll
            for (int r = 0; r < 4; ++r) {
                float s = ze[p][r] * sigm(ze[p + 2][r]) + zo[p][r] * sigm(zo[p + 2][r]);
                gate[gi][p][r] = sigm(s);
            }
    }
    __shared__ bf16_t mT[32][64];
    __shared__ bf16_t hT[32][64];
#pragma unroll
    for (int p = 0; p < 2; ++p)
#pragma unroll
        for (int r = 0; r < 4; ++r) {
            const int row = nw + quad * 4 + r, col = p * 16 + mrow;
            const size_t ci = ((size_t)b * NN + row) * FF + col;
            const float i2 = gate[0][p][r], gg = gate[1][p][r], o2 = gate[2][p][r];
            float mn = i2 * m[ci] + (1.f - i2) * gg;
            m[ci] = mn;
            float hn = mn * o2;
            hs[(((size_t)b * TT + t) * NN + row) * FF + col] = hn;
            mT[col][wave * 16 + quad * 4 + r] = (bf16_t)mn;
            hT[col][wave * 16 + quad * 4 + r] = (bf16_t)hn;
        }
    __syncthreads();
    {
        const int col = tid >> 3, seg = tid & 7;
        union { uint4 u; bf16_t h[8]; } om, oh;
#pragma unroll
        for (int j = 0; j < 8; ++j) { om.h[j] = mT[col][seg * 8 + j]; oh.h[j] = hT[col][seg * 8 + j]; }
        *(uint4*)&hm_bf[((size_t)b * 64 + 32 + col) * NN + n0 + seg * 8] = om.u;
        *(uint4*)&h_bf[((size_t)b * FF + col) * NN + n0 + seg * 8] = oh.u;
    }
}

// ---------------- tail: last_h / last_c / last_m ----------------------------
__global__ __launch_bounds__(256) void finalize_k(const float* __restrict__ hs,
                                                  const float* __restrict__ c,
                                                  const float* __restrict__ m,
                                                  float* __restrict__ tail) {
    const int idx = blockIdx.x * 256 + threadIdx.x;   // 524288
    const int b = idx >> 17, r = idx & 131071;
    tail[idx] = hs[((size_t)b * TT + (TT - 1)) * 131072 + r];
    tail[524288 + idx] = c[idx];
    tail[1048576 + idx] = m[idx];
}

// ---------------------------------------------------------------------------
extern "C" void kernel_launch(void* const* d_in, const int* in_sizes, int n_in,
                              void* d_out, int out_size, void* d_ws, size_t ws_size,
                              hipStream_t stream) {
    const float* x    = (const float*)d_in[0];   // [4,12,4096,32]
    const float* adj  = (const float*)d_in[1];   // [4,4096,4096]
    const float* W    = (const float*)d_in[2];   // [14,32,64]
    const float* bias = (const float*)d_in[3];   // [14,64]
    float* out = (float*)d_out;

    char* ws = (char*)d_ws;
    size_t off = 0;
    auto carve = [&](size_t bytes) -> void* {
        void* p = ws + off;
        off += (bytes + 255) & ~(size_t)255;
        return p;
    };
    bf16_t* xT    = (bf16_t*)carve((size_t)BB * 384 * NN * 2);       // 12.6 MB
    float*  Y1    = (float*)carve((size_t)BB * 4 * NN * 64 * 4);     // 16 MB
    float*  Y2    = (float*)carve((size_t)BB * 4 * NN * 64 * 4);     // 16 MB
    bf16_t* h_bf  = (bf16_t*)carve((size_t)BB * FF * NN * 2);        // 1 MB
    bf16_t* hm_bf = (bf16_t*)carve((size_t)BB * 64 * NN * 2);        // 2 MB
    bf16_t* Wf    = (bf16_t*)carve((size_t)14 * 4 * 64 * 8 * 2);
    float*  cbuf  = (float*)carve((size_t)BB * NN * FF * 4);         // 2 MB
    float*  mbuf  = (float*)carve((size_t)BB * NN * FF * 4);         // 2 MB
    const size_t adj_bytes = (size_t)BB * NN * NN * 2;               // 134 MB
    const bool abf = (ws_size >= off + adj_bytes);
    bf16_t* adj_bf = abf ? (bf16_t*)carve(adj_bytes) : nullptr;

    if (abf) conv_adj_k<<<32768, 256, 0, stream>>>(adj, adj_bf);
    make_wfrag_k<<<14, 256, 0, stream>>>(W, Wf);
    xpose_k<<<dim3(64, TT, BB), 256, 0, stream>>>(x, xT);
    init_k<<<2048, 256, 0, stream>>>(h_bf, hm_bf, cbuf, mbuf);

    const dim3 ggrid(64, 4, BB);
    for (int t = 0; t < TT; ++t) {
        const bf16_t* xts = xT + (size_t)t * 32 * NN;
        if (abf) gemm_direct<true, 32, 32, 384><<<ggrid, 256, 0, stream>>>(adj_bf, h_bf, xts, Y1);
        else     gemm_direct<false, 32, 32, 384><<<ggrid, 256, 0, stream>>>(adj, h_bf, xts, Y1);
        gates1_k<<<dim3(64, BB), 256, 0, stream>>>(Y1, Wf, bias, cbuf, hm_bf);
        if (abf) gemm_direct<true, 64, 64, 64><<<ggrid, 256, 0, stream>>>(adj_bf, hm_bf, hm_bf, Y2);
        else     gemm_direct<false, 64, 64, 64><<<ggrid, 256, 0, stream>>>(adj, hm_bf, hm_bf, Y2);
        gates2_k<<<dim3(64, BB), 256, 0, stream>>>(Y2, Wf, bias, mbuf, hm_bf, h_bf, out, t);
    }
    finalize_k<<<2048, 256, 0, stream>>>(out, cbuf, mbuf, out + (size_t)BB * TT * NN * FF);
}